// Round 10
// baseline (243.665 us; speedup 1.0000x reference)
//
#include <hip/hip_runtime.h>

typedef __attribute__((ext_vector_type(8))) short bf16x8;
typedef __attribute__((ext_vector_type(4))) float f32x4;
typedef unsigned short u16;
typedef unsigned int u32;

#define MFMA16(A, B, C) __builtin_amdgcn_mfma_f32_16x16x32_bf16((A), (B), (C), 0, 0, 0)

#if __has_builtin(__builtin_amdgcn_exp2f)
#define EXP2(x) __builtin_amdgcn_exp2f(x)
#else
#define EXP2(x) exp2f(x)
#endif

__device__ __forceinline__ u16 f2bf(float f) {
  union { float f; unsigned u; } x; x.f = f;
  unsigned r = (x.u + 0x7fffu + ((x.u >> 16) & 1u)) >> 16;
  return (u16)r;
}
__device__ __forceinline__ float bf2f(u16 h) {
  union { float f; unsigned u; } x; x.u = ((unsigned)h) << 16;
  return x.f;
}

// ---------------- prep kernels ----------------

__global__ __launch_bounds__(256) void cast_x_kernel(const float* __restrict__ x,
                                                     u16* __restrict__ xb, int n4) {
  int i = blockIdx.x * 256 + threadIdx.x;
  if (i >= n4) return;
  float4 v = ((const float4*)x)[i];
  ushort4 o;
  o.x = f2bf(v.x); o.y = f2bf(v.y); o.z = f2bf(v.z); o.w = f2bf(v.w);
  ((ushort4*)xb)[i] = o;
}

// W_attn [512][1536] -> wta [1536][512] bf16, tiled 64x64 transpose
__global__ __launch_bounds__(256) void trans_wa_kernel(const float* __restrict__ W,
                                                       u16* __restrict__ wta) {
  __shared__ u16 T[64][72];
  const int n0 = blockIdx.x * 64;
  const int k0 = blockIdx.y * 64;
  const int tid = threadIdx.x;
  const int r = tid >> 4, c4 = (tid & 15) * 4;
#pragma unroll
  for (int i = 0; i < 4; i++) {
    int row = r + i * 16;
    float4 v = *(const float4*)&W[(size_t)(k0 + row) * 1536 + n0 + c4];
    T[c4 + 0][row] = f2bf(v.x);
    T[c4 + 1][row] = f2bf(v.y);
    T[c4 + 2][row] = f2bf(v.z);
    T[c4 + 3][row] = f2bf(v.w);
  }
  __syncthreads();
  const int row = tid >> 2, c16 = (tid & 3) * 16;
  *(uint4*)&wta[(size_t)(n0 + row) * 512 + k0 + c16]     = *(uint4*)&T[row][c16];
  *(uint4*)&wta[(size_t)(n0 + row) * 512 + k0 + c16 + 8] = *(uint4*)&T[row][c16 + 8];
}

// W_out [512][512] -> whi/wlo [512][512] bf16 transposed, tiled
__global__ __launch_bounds__(256) void trans_wo_kernel(const float* __restrict__ W,
                                                       u16* __restrict__ whi,
                                                       u16* __restrict__ wlo) {
  __shared__ u16 Th[64][72];
  __shared__ u16 Tl[64][72];
  const int n0 = blockIdx.x * 64;
  const int k0 = blockIdx.y * 64;
  const int tid = threadIdx.x;
  const int r = tid >> 4, c4 = (tid & 15) * 4;
#pragma unroll
  for (int i = 0; i < 4; i++) {
    int row = r + i * 16;
    float4 v = *(const float4*)&W[(size_t)(k0 + row) * 512 + n0 + c4];
    float vv[4] = {v.x, v.y, v.z, v.w};
#pragma unroll
    for (int jj = 0; jj < 4; jj++) {
      u16 hi = f2bf(vv[jj]);
      Th[c4 + jj][row] = hi;
      Tl[c4 + jj][row] = f2bf(vv[jj] - bf2f(hi));
    }
  }
  __syncthreads();
  const int row = tid >> 2, c16 = (tid & 3) * 16;
  *(uint4*)&whi[(size_t)(n0 + row) * 512 + k0 + c16]     = *(uint4*)&Th[row][c16];
  *(uint4*)&whi[(size_t)(n0 + row) * 512 + k0 + c16 + 8] = *(uint4*)&Th[row][c16 + 8];
  *(uint4*)&wlo[(size_t)(n0 + row) * 512 + k0 + c16]     = *(uint4*)&Tl[row][c16];
  *(uint4*)&wlo[(size_t)(n0 + row) * 512 + k0 + c16 + 8] = *(uint4*)&Tl[row][c16 + 8];
}

// ---------------- QKV GEMM (64x64 tile, dbuf, XCD-banded) ----------------
// Q: scaled by 0.125*log2(e), [bh][t][64]
// K: frag-packed K'[bh]: idx = (it*16 + jt*2 + ks)*512 + (t&15)*32 + (d&31)
// V: frag-packed V'[bh][it][ks][d][quad][jj]
__global__ __launch_bounds__(256) void gemm_qkv(const u16* __restrict__ xb,
                                                const u16* __restrict__ wta,
                                                const float* __restrict__ b_attn,
                                                u16* __restrict__ q,
                                                u16* __restrict__ kk,
                                                u16* __restrict__ v) {
  __shared__ u16 A_lds[2][64 * 72];
  __shared__ u16 B_lds[2][64 * 72];
  // XCD banding: each XCD owns a 16-m-tile stripe -> A stripe L2-resident
  const int bid = blockIdx.x;
  const int xcd = bid & 7, rr = bid >> 3;
  const int m0 = (xcd * 16 + (rr & 15)) * 64;
  const int n0 = (rr >> 4) * 64;
  const int tid  = threadIdx.x;
  const int lane = tid & 63, w = tid >> 6;
  const int wm = w >> 1, wn = w & 1;
  const int quad = lane >> 4, l15 = lane & 15;

  f32x4 acc[2][2] = {};

  uint4 ra[2], rb[2];
#pragma unroll
  for (int i = 0; i < 2; i++) {
    int vv = tid + i * 256;
    int row = vv >> 3, cv = (vv & 7) * 8;
    ra[i] = *(const uint4*)(xb  + (size_t)(m0 + row) * 512 + cv);
    rb[i] = *(const uint4*)(wta + (size_t)(n0 + row) * 512 + cv);
  }

  for (int kt = 0; kt < 8; kt++) {
    u16* Ab = A_lds[kt & 1];
    u16* Bb = B_lds[kt & 1];
#pragma unroll
    for (int i = 0; i < 2; i++) {
      int vv = tid + i * 256;
      int row = vv >> 3, cv = (vv & 7) * 8;
      *(uint4*)&Ab[row * 72 + cv] = ra[i];
      *(uint4*)&Bb[row * 72 + cv] = rb[i];
    }
    __syncthreads();
    if (kt < 7) {
      int k0 = (kt + 1) * 64;
#pragma unroll
      for (int i = 0; i < 2; i++) {
        int vv = tid + i * 256;
        int row = vv >> 3, cv = (vv & 7) * 8;
        ra[i] = *(const uint4*)(xb  + (size_t)(m0 + row) * 512 + k0 + cv);
        rb[i] = *(const uint4*)(wta + (size_t)(n0 + row) * 512 + k0 + cv);
      }
    }
#pragma unroll
    for (int ks = 0; ks < 2; ks++) {
      bf16x8 af[2], bf[2];
#pragma unroll
      for (int ri = 0; ri < 2; ri++)
        af[ri] = *(const bf16x8*)&Ab[(wm * 32 + ri * 16 + l15) * 72 + ks * 32 + quad * 8];
#pragma unroll
      for (int ci = 0; ci < 2; ci++)
        bf[ci] = *(const bf16x8*)&Bb[(wn * 32 + ci * 16 + l15) * 72 + ks * 32 + quad * 8];
#pragma unroll
      for (int ri = 0; ri < 2; ri++)
#pragma unroll
        for (int ci = 0; ci < 2; ci++)
          acc[ri][ci] = MFMA16(af[ri], bf[ci], acc[ri][ci]);
    }
  }

  const float QS = 0.18033688011112043f;  // 0.125 * log2(e)
#pragma unroll
  for (int ri = 0; ri < 2; ri++) {
#pragma unroll
    for (int ci = 0; ci < 2; ci++) {
      int n = n0 + wn * 32 + ci * 16 + l15;
      float bias = b_attn[n];
      int chunk = n >> 9;
      int c = n & 511;
      int h = c >> 6, d = c & 63;
      int m_base = m0 + wm * 32 + ri * 16 + quad * 4;
      int b = m_base >> 11, t0 = m_base & 2047;
      int bh = b * 8 + h;
      if (chunk == 0) {
#pragma unroll
        for (int r = 0; r < 4; r++)
          q[(size_t)(bh * 2048 + t0 + r) * 64 + d] = f2bf((acc[ri][ci][r] + bias) * QS);
      } else if (chunk == 1) {
        // K' frag-packed
        int ks2 = d >> 5, within = d & 31;
#pragma unroll
        for (int r = 0; r < 4; r++) {
          int t = t0 + r;
          size_t idx = (size_t)((t >> 7) * 16 + ((t >> 4) & 7) * 2 + ks2) * 512
                       + (t & 15) * 32 + within;
          kk[(size_t)bh * 131072 + idx] = f2bf(acc[ri][ci][r] + bias);
        }
      } else {
        int it = t0 >> 7, ks2 = (t0 >> 5) & 3, qd = (t0 >> 3) & 3, jj = t0 & 7;
        ushort4 pk;
        pk.x = f2bf(acc[ri][ci][0] + bias);
        pk.y = f2bf(acc[ri][ci][1] + bias);
        pk.z = f2bf(acc[ri][ci][2] + bias);
        pk.w = f2bf(acc[ri][ci][3] + bias);
        size_t idx = ((((size_t)bh * 16 + it) * 4 + ks2) * 64 + d) * 32 + qd * 8 + jj;
        *(ushort4*)&v[idx] = pk;
      }
    }
  }
}

// ---------------- flash attention (barrier-free, frag-packed K'+V') -------
// grid 1024 (XCD-swizzled), 4 waves x 16 q-rows, 128-wide KV tiles.
// K' and V' loaded direct from global as contiguous 1-KB wave loads (L2/L1);
// NO __syncthreads. P per-wave LDS. Raw s_barrier = scheduling rendezvous
// only (no cross-wave data deps) to keep waves lockstep for L1 dedup.
__global__ __launch_bounds__(256, 4) void flash_attn(const u16* __restrict__ q,
                                                     const u16* __restrict__ k,
                                                     const u16* __restrict__ vt,
                                                     u16* __restrict__ yb) {
  __shared__ u16 P_lds[4 * 16 * 136];  // per-wave [16 q][128 j +pad]

  const int flat = blockIdx.y * 32 + blockIdx.x;
  const int bh = (flat & 7) * 4 + ((flat >> 3) & 3);
  const int qt = flat >> 5;

  const int tid  = threadIdx.x;
  const int lane = tid & 63, w = tid >> 6;
  const int quad = lane >> 4, l15 = lane & 15;

  const u16* qp = q  + (size_t)bh * 131072;
  const u16* kp = k  + (size_t)bh * 131072;
  const u16* vp = vt + (size_t)bh * 131072;

  bf16x8 qf[2];
#pragma unroll
  for (int ks = 0; ks < 2; ks++)
    qf[ks] = *(const bf16x8*)(qp + (size_t)(qt * 64 + w * 16 + l15) * 64 + ks * 32 + quad * 8);

  f32x4 l_acc = {};
  f32x4 o[4] = {};

  bf16x8 ones;
  {
    short one = (short)0x3F80;
    ones = (bf16x8){one, one, one, one, one, one, one, one};
  }

  u16* Pw = &P_lds[w * 16 * 136];
  const int koff = l15 * 32 + quad * 8;   // lane offset inside a 1-KB K' chunk

  for (int it = 0; it < 16; it++) {
    __builtin_amdgcn_s_barrier();   // rendezvous only — no memory semantics needed
    const u16* kit = kp + it * 8192;
    const u16* vit = vp + it * 8192;

    bf16x8 vf[2][4];
#pragma unroll
    for (int dt = 0; dt < 4; dt++)
      vf[0][dt] = *(const bf16x8*)(vit + (dt * 16 + l15) * 32 + quad * 8);

    // S^T streamed over jt: K' frag load -> MFMA -> exp2 -> pack -> P write
#pragma unroll
    for (int jt = 0; jt < 8; jt++) {
      bf16x8 kf0 = *(const bf16x8*)(kit + (jt * 2 + 0) * 512 + koff);
      bf16x8 kf1 = *(const bf16x8*)(kit + (jt * 2 + 1) * 512 + koff);
      f32x4 s = {0.f, 0.f, 0.f, 0.f};
      s = MFMA16(kf0, qf[0], s);
      s = MFMA16(kf1, qf[1], s);
      u32 pb[4];
#pragma unroll
      for (int r = 0; r < 4; r++) pb[r] = __float_as_uint(EXP2(s[r]));
      uint2 pk;
      pk.x = __builtin_amdgcn_perm(pb[1], pb[0], 0x07060302u);
      pk.y = __builtin_amdgcn_perm(pb[3], pb[2], 0x07060302u);
      *(uint2*)&Pw[l15 * 136 + jt * 16 + quad * 4] = pk;
    }

    // O += P·V ; l += P·1   (vf double-buffered)
#pragma unroll
    for (int ks = 0; ks < 4; ks++) {
      if (ks < 3) {
#pragma unroll
        for (int dt = 0; dt < 4; dt++)
          vf[(ks + 1) & 1][dt] = *(const bf16x8*)(vit + (ks + 1) * 2048 + (dt * 16 + l15) * 32 + quad * 8);
      }
      bf16x8 pf = *(const bf16x8*)&Pw[l15 * 136 + ks * 32 + quad * 8];
      l_acc = MFMA16(pf, ones, l_acc);
#pragma unroll
      for (int dt = 0; dt < 4; dt++)
        o[dt] = MFMA16(pf, vf[ks & 1][dt], o[dt]);
    }
  }

  // epilogue: normalize, transpose via per-wave LDS, write yhi/ylo planes
  const int b = bh >> 3, h = bh & 7;
  u32* Tw = (u32*)Pw;
#pragma unroll
  for (int r = 0; r < 4; r++) {
    float inv = 1.f / l_acc[r];
#pragma unroll
    for (int dt = 0; dt < 4; dt++) {
      float val = o[dt][r] * inv;
      u16 hi = f2bf(val);
      u16 lo = f2bf(val - bf2f(hi));
      Tw[(quad * 4 + r) * 68 + dt * 16 + l15] = (u32)hi | ((u32)lo << 16);
    }
  }
  int t = qt * 64 + w * 16 + l15;
  size_t rowb = (size_t)(b * 2048 + t) * 512 + h * 64 + quad * 16;
  uint4 g0 = *(uint4*)&Tw[l15 * 68 + quad * 16 + 0];
  uint4 g1 = *(uint4*)&Tw[l15 * 68 + quad * 16 + 4];
  uint4 g2 = *(uint4*)&Tw[l15 * 68 + quad * 16 + 8];
  uint4 g3 = *(uint4*)&Tw[l15 * 68 + quad * 16 + 12];
  uint4 hi4, lo4;
  hi4.x = __builtin_amdgcn_perm(g0.y, g0.x, 0x05040100u);
  hi4.y = __builtin_amdgcn_perm(g0.w, g0.z, 0x05040100u);
  hi4.z = __builtin_amdgcn_perm(g1.y, g1.x, 0x05040100u);
  hi4.w = __builtin_amdgcn_perm(g1.w, g1.z, 0x05040100u);
  lo4.x = __builtin_amdgcn_perm(g0.y, g0.x, 0x07060302u);
  lo4.y = __builtin_amdgcn_perm(g0.w, g0.z, 0x07060302u);
  lo4.z = __builtin_amdgcn_perm(g1.y, g1.x, 0x07060302u);
  lo4.w = __builtin_amdgcn_perm(g1.w, g1.z, 0x07060302u);
  *(uint4*)&yb[rowb] = hi4;
  *(uint4*)&yb[(size_t)4 * 2048 * 512 + rowb] = lo4;
  hi4.x = __builtin_amdgcn_perm(g2.y, g2.x, 0x05040100u);
  hi4.y = __builtin_amdgcn_perm(g2.w, g2.z, 0x05040100u);
  hi4.z = __builtin_amdgcn_perm(g3.y, g3.x, 0x05040100u);
  hi4.w = __builtin_amdgcn_perm(g3.w, g3.z, 0x05040100u);
  lo4.x = __builtin_amdgcn_perm(g2.y, g2.x, 0x07060302u);
  lo4.y = __builtin_amdgcn_perm(g2.w, g2.z, 0x07060302u);
  lo4.z = __builtin_amdgcn_perm(g3.y, g3.x, 0x07060302u);
  lo4.w = __builtin_amdgcn_perm(g3.w, g3.z, 0x07060302u);
  *(uint4*)&yb[rowb + 8] = hi4;
  *(uint4*)&yb[(size_t)4 * 2048 * 512 + rowb + 8] = lo4;
}

// ---------------- output projection (R6 4-buffer hi/lo, XCD-banded) ------
__global__ __launch_bounds__(256) void gemm_out(const u16* __restrict__ yhi,
                                                const u16* __restrict__ ylo,
                                                const u16* __restrict__ whi,
                                                const u16* __restrict__ wlo,
                                                const float* __restrict__ b_out,
                                                float* __restrict__ out) {
  __shared__ u16 Ah[64 * 72];
  __shared__ u16 Al[64 * 72];
  __shared__ u16 Bh[64 * 72];
  __shared__ u16 Bl[64 * 72];
  const int bid = blockIdx.x;
  const int xcd = bid & 7, rr = bid >> 3;
  const int m0 = (xcd * 16 + (rr & 15)) * 64;
  const int n0 = (rr >> 4) * 64;
  const int tid  = threadIdx.x;
  const int lane = tid & 63, w = tid >> 6;
  const int wm = w >> 1, wn = w & 1;
  const int quad = lane >> 4, l15 = lane & 15;

  f32x4 acc[2][2] = {};

  for (int k0 = 0; k0 < 512; k0 += 64) {
#pragma unroll
    for (int i = 0; i < 2; i++) {
      int vv = tid + i * 256;
      int row = vv >> 3;
      int cv  = (vv & 7) * 8;
      *(uint4*)&Ah[row * 72 + cv] = *(const uint4*)(yhi + (size_t)(m0 + row) * 512 + k0 + cv);
      *(uint4*)&Al[row * 72 + cv] = *(const uint4*)(ylo + (size_t)(m0 + row) * 512 + k0 + cv);
      *(uint4*)&Bh[row * 72 + cv] = *(const uint4*)(whi + (size_t)(n0 + row) * 512 + k0 + cv);
      *(uint4*)&Bl[row * 72 + cv] = *(const uint4*)(wlo + (size_t)(n0 + row) * 512 + k0 + cv);
    }
    __syncthreads();
#pragma unroll
    for (int ks = 0; ks < 2; ks++) {
      bf16x8 afh[2], afl[2], bfh[2], bfl[2];
#pragma unroll
      for (int ri = 0; ri < 2; ri++) {
        afh[ri] = *(const bf16x8*)&Ah[(wm * 32 + ri * 16 + l15) * 72 + ks * 32 + quad * 8];
        afl[ri] = *(const bf16x8*)&Al[(wm * 32 + ri * 16 + l15) * 72 + ks * 32 + quad * 8];
      }
#pragma unroll
      for (int ci = 0; ci < 2; ci++) {
        bfh[ci] = *(const bf16x8*)&Bh[(wn * 32 + ci * 16 + l15) * 72 + ks * 32 + quad * 8];
        bfl[ci] = *(const bf16x8*)&Bl[(wn * 32 + ci * 16 + l15) * 72 + ks * 32 + quad * 8];
      }
#pragma unroll
      for (int ri = 0; ri < 2; ri++)
#pragma unroll
        for (int ci = 0; ci < 2; ci++) {
          acc[ri][ci] = MFMA16(afh[ri], bfh[ci], acc[ri][ci]);
          acc[ri][ci] = MFMA16(afh[ri], bfl[ci], acc[ri][ci]);
          acc[ri][ci] = MFMA16(afl[ri], bfh[ci], acc[ri][ci]);
        }
    }
    __syncthreads();
  }

#pragma unroll
  for (int ri = 0; ri < 2; ri++) {
#pragma unroll
    for (int ci = 0; ci < 2; ci++) {
      int n = n0 + wn * 32 + ci * 16 + l15;
      float bias = b_out[n];
#pragma unroll
      for (int r = 0; r < 4; r++) {
        int m = m0 + wm * 32 + ri * 16 + quad * 4 + r;
        out[(size_t)m * 512 + n] = acc[ri][ci][r] + bias;
      }
    }
  }
}

// ---------------- launch ----------------
extern "C" void kernel_launch(void* const* d_in, const int* in_sizes, int n_in,
                              void* d_out, int out_size, void* d_ws, size_t ws_size,
                              hipStream_t stream) {
  const float* x      = (const float*)d_in[0];
  const float* W_attn = (const float*)d_in[1];
  const float* b_attn = (const float*)d_in[2];
  const float* W_out  = (const float*)d_in[3];
  const float* b_out  = (const float*)d_in[4];
  float* out = (float*)d_out;

  char* ws = (char*)d_ws;
  u16* xb   = (u16*)(ws + 0);                 //  8 MB  [8192][512]
  u16* wta  = (u16*)(ws + 8388608);           //  1.5MB [1536][512]
  u16* wtoh = (u16*)(ws + 9961472);           //  0.5MB [512][512]
  u16* wtol = (u16*)(ws + 10485760);          //  0.5MB
  u16* qb   = (u16*)(ws + 11010048);          //  8 MB  [bh][t][64] (pre-scaled)
  u16* kb   = (u16*)(ws + 19398656);          //  8 MB  K' frag-packed
  u16* vtb  = (u16*)(ws + 27787264);          //  8 MB  V' frag-packed
  u16* yhi  = (u16*)(ws + 36175872);          //  8 MB  [B,T,C] (+8 MB lo plane)

  cast_x_kernel<<<4096, 256, 0, stream>>>(x, xb, 4 * 2048 * 512 / 4);
  trans_wa_kernel<<<dim3(24, 8), 256, 0, stream>>>(W_attn, wta);
  trans_wo_kernel<<<dim3(8, 8), 256, 0, stream>>>(W_out, wtoh, wtol);
  gemm_qkv<<<3072, 256, 0, stream>>>(xb, wta, b_attn, qb, kb, vtb);
  flash_attn<<<dim3(32, 32), 256, 0, stream>>>(qb, kb, vtb, yhi);
  gemm_out<<<1024, 256, 0, stream>>>(yhi, yhi + (size_t)4 * 2048 * 512, wtoh, wtol, b_out, out);
}

// Round 11
// 201.856 us; speedup vs baseline: 1.2071x; 1.2071x over previous
//
#include <hip/hip_runtime.h>

typedef __attribute__((ext_vector_type(8))) short bf16x8;
typedef __attribute__((ext_vector_type(4))) float f32x4;
typedef unsigned short u16;
typedef unsigned int u32;

#define MFMA16(A, B, C) __builtin_amdgcn_mfma_f32_16x16x32_bf16((A), (B), (C), 0, 0, 0)

#if __has_builtin(__builtin_amdgcn_exp2f)
#define EXP2(x) __builtin_amdgcn_exp2f(x)
#else
#define EXP2(x) exp2f(x)
#endif

typedef __attribute__((address_space(3))) unsigned int lds_u32;
typedef const __attribute__((address_space(1))) unsigned int glb_u32;

__device__ __forceinline__ u16 f2bf(float f) {
  union { float f; unsigned u; } x; x.f = f;
  unsigned r = (x.u + 0x7fffu + ((x.u >> 16) & 1u)) >> 16;
  return (u16)r;
}
__device__ __forceinline__ float bf2f(u16 h) {
  union { float f; unsigned u; } x; x.u = ((unsigned)h) << 16;
  return x.f;
}

// stage a 128x64 bf16 tile into contiguous LDS via global_load_lds width=16,
// XOR-swizzled: LDS slot (row, c) holds global chunk c^(row&7).
__device__ __forceinline__ void stage_sw(const u16* src, int ld, u16* lds, int tid) {
#pragma unroll
  for (int i = 0; i < 4; i++) {
    int vv = tid + i * 256;
    int row = vv >> 3, c = vv & 7;
    const u16* gp = src + (size_t)row * ld + (size_t)(c ^ (row & 7)) * 8;
    __builtin_amdgcn_global_load_lds((glb_u32*)gp,
        (lds_u32*)(lds + (size_t)(i * 256 + (tid & 192)) * 8), 16, 0, 0);
  }
}

// ---------------- prep kernels ----------------

__global__ __launch_bounds__(256) void cast_x_kernel(const float* __restrict__ x,
                                                     u16* __restrict__ xb, int n4) {
  int i = blockIdx.x * 256 + threadIdx.x;
  if (i >= n4) return;
  float4 v = ((const float4*)x)[i];
  ushort4 o;
  o.x = f2bf(v.x); o.y = f2bf(v.y); o.z = f2bf(v.z); o.w = f2bf(v.w);
  ((ushort4*)xb)[i] = o;
}

// W_attn [512][1536] -> wta [1536][512] bf16, tiled 64x64 transpose
__global__ __launch_bounds__(256) void trans_wa_kernel(const float* __restrict__ W,
                                                       u16* __restrict__ wta) {
  __shared__ u16 T[64][72];
  const int n0 = blockIdx.x * 64;
  const int k0 = blockIdx.y * 64;
  const int tid = threadIdx.x;
  const int r = tid >> 4, c4 = (tid & 15) * 4;
#pragma unroll
  for (int i = 0; i < 4; i++) {
    int row = r + i * 16;
    float4 v = *(const float4*)&W[(size_t)(k0 + row) * 1536 + n0 + c4];
    T[c4 + 0][row] = f2bf(v.x);
    T[c4 + 1][row] = f2bf(v.y);
    T[c4 + 2][row] = f2bf(v.z);
    T[c4 + 3][row] = f2bf(v.w);
  }
  __syncthreads();
  const int row = tid >> 2, c16 = (tid & 3) * 16;
  *(uint4*)&wta[(size_t)(n0 + row) * 512 + k0 + c16]     = *(uint4*)&T[row][c16];
  *(uint4*)&wta[(size_t)(n0 + row) * 512 + k0 + c16 + 8] = *(uint4*)&T[row][c16 + 8];
}

// W_out [512][512] -> whi/wlo [512][512] bf16 transposed, tiled
__global__ __launch_bounds__(256) void trans_wo_kernel(const float* __restrict__ W,
                                                       u16* __restrict__ whi,
                                                       u16* __restrict__ wlo) {
  __shared__ u16 Th[64][72];
  __shared__ u16 Tl[64][72];
  const int n0 = blockIdx.x * 64;
  const int k0 = blockIdx.y * 64;
  const int tid = threadIdx.x;
  const int r = tid >> 4, c4 = (tid & 15) * 4;
#pragma unroll
  for (int i = 0; i < 4; i++) {
    int row = r + i * 16;
    float4 v = *(const float4*)&W[(size_t)(k0 + row) * 512 + n0 + c4];
    float vv[4] = {v.x, v.y, v.z, v.w};
#pragma unroll
    for (int jj = 0; jj < 4; jj++) {
      u16 hi = f2bf(vv[jj]);
      Th[c4 + jj][row] = hi;
      Tl[c4 + jj][row] = f2bf(vv[jj] - bf2f(hi));
    }
  }
  __syncthreads();
  const int row = tid >> 2, c16 = (tid & 3) * 16;
  *(uint4*)&whi[(size_t)(n0 + row) * 512 + k0 + c16]     = *(uint4*)&Th[row][c16];
  *(uint4*)&whi[(size_t)(n0 + row) * 512 + k0 + c16 + 8] = *(uint4*)&Th[row][c16 + 8];
  *(uint4*)&wlo[(size_t)(n0 + row) * 512 + k0 + c16]     = *(uint4*)&Tl[row][c16];
  *(uint4*)&wlo[(size_t)(n0 + row) * 512 + k0 + c16 + 8] = *(uint4*)&Tl[row][c16 + 8];
}

// ---------------- QKV GEMM (64x64 tile, dbuf, XCD-banded) ----------------
// Q: scaled by 0.125*log2(e), [bh][t][64]
// K: [bh][t][64]
// V: frag-packed V'[bh][it][ks][d][quad][jj]
__global__ __launch_bounds__(256) void gemm_qkv(const u16* __restrict__ xb,
                                                const u16* __restrict__ wta,
                                                const float* __restrict__ b_attn,
                                                u16* __restrict__ q,
                                                u16* __restrict__ kk,
                                                u16* __restrict__ v) {
  __shared__ u16 A_lds[2][64 * 72];
  __shared__ u16 B_lds[2][64 * 72];
  // XCD banding: each XCD owns a 16-m-tile stripe -> A stripe L2-resident
  const int bid = blockIdx.x;
  const int xcd = bid & 7, rr = bid >> 3;
  const int m0 = (xcd * 16 + (rr & 15)) * 64;
  const int n0 = (rr >> 4) * 64;
  const int tid  = threadIdx.x;
  const int lane = tid & 63, w = tid >> 6;
  const int wm = w >> 1, wn = w & 1;
  const int quad = lane >> 4, l15 = lane & 15;

  f32x4 acc[2][2] = {};

  uint4 ra[2], rb[2];
#pragma unroll
  for (int i = 0; i < 2; i++) {
    int vv = tid + i * 256;
    int row = vv >> 3, cv = (vv & 7) * 8;
    ra[i] = *(const uint4*)(xb  + (size_t)(m0 + row) * 512 + cv);
    rb[i] = *(const uint4*)(wta + (size_t)(n0 + row) * 512 + cv);
  }

  for (int kt = 0; kt < 8; kt++) {
    u16* Ab = A_lds[kt & 1];
    u16* Bb = B_lds[kt & 1];
#pragma unroll
    for (int i = 0; i < 2; i++) {
      int vv = tid + i * 256;
      int row = vv >> 3, cv = (vv & 7) * 8;
      *(uint4*)&Ab[row * 72 + cv] = ra[i];
      *(uint4*)&Bb[row * 72 + cv] = rb[i];
    }
    __syncthreads();
    if (kt < 7) {
      int k0 = (kt + 1) * 64;
#pragma unroll
      for (int i = 0; i < 2; i++) {
        int vv = tid + i * 256;
        int row = vv >> 3, cv = (vv & 7) * 8;
        ra[i] = *(const uint4*)(xb  + (size_t)(m0 + row) * 512 + k0 + cv);
        rb[i] = *(const uint4*)(wta + (size_t)(n0 + row) * 512 + k0 + cv);
      }
    }
#pragma unroll
    for (int ks = 0; ks < 2; ks++) {
      bf16x8 af[2], bf[2];
#pragma unroll
      for (int ri = 0; ri < 2; ri++)
        af[ri] = *(const bf16x8*)&Ab[(wm * 32 + ri * 16 + l15) * 72 + ks * 32 + quad * 8];
#pragma unroll
      for (int ci = 0; ci < 2; ci++)
        bf[ci] = *(const bf16x8*)&Bb[(wn * 32 + ci * 16 + l15) * 72 + ks * 32 + quad * 8];
#pragma unroll
      for (int ri = 0; ri < 2; ri++)
#pragma unroll
        for (int ci = 0; ci < 2; ci++)
          acc[ri][ci] = MFMA16(af[ri], bf[ci], acc[ri][ci]);
    }
  }

  const float QS = 0.18033688011112043f;  // 0.125 * log2(e)
#pragma unroll
  for (int ri = 0; ri < 2; ri++) {
#pragma unroll
    for (int ci = 0; ci < 2; ci++) {
      int n = n0 + wn * 32 + ci * 16 + l15;
      float bias = b_attn[n];
      int chunk = n >> 9;
      int c = n & 511;
      int h = c >> 6, d = c & 63;
      int m_base = m0 + wm * 32 + ri * 16 + quad * 4;
      int b = m_base >> 11, t0 = m_base & 2047;
      int bh = b * 8 + h;
      if (chunk == 0) {
#pragma unroll
        for (int r = 0; r < 4; r++)
          q[(size_t)(bh * 2048 + t0 + r) * 64 + d] = f2bf((acc[ri][ci][r] + bias) * QS);
      } else if (chunk == 1) {
#pragma unroll
        for (int r = 0; r < 4; r++)
          kk[(size_t)(bh * 2048 + t0 + r) * 64 + d] = f2bf(acc[ri][ci][r] + bias);
      } else {
        int it = t0 >> 7, ks2 = (t0 >> 5) & 3, qd = (t0 >> 3) & 3, jj = t0 & 7;
        ushort4 pk;
        pk.x = f2bf(acc[ri][ci][0] + bias);
        pk.y = f2bf(acc[ri][ci][1] + bias);
        pk.z = f2bf(acc[ri][ci][2] + bias);
        pk.w = f2bf(acc[ri][ci][3] + bias);
        size_t idx = ((((size_t)bh * 16 + it) * 4 + ks2) * 64 + d) * 32 + qd * 8 + jj;
        *(ushort4*)&v[idx] = pk;
      }
    }
  }
}

// ---------------- flash attention ----------------
// R9 structure (32 q-rows/wave, K dbuf via global_load_lds, V' direct) but
// the two q-halves share ONE per-wave 16-row P buffer sequentially:
// LDS = 32K (K dbuf) + 17.4K (P) = 49.2 KB -> 3 blocks/CU (was 2).
__global__ __launch_bounds__(256, 3) void flash_attn(const u16* __restrict__ q,
                                                     const u16* __restrict__ k,
                                                     const u16* __restrict__ vt,
                                                     u16* __restrict__ yb) {
  __shared__ u16 K_lds[2][128 * 64];
  __shared__ u16 P_lds[4 * 16 * 136];  // per-wave [16 q][128 j +pad]

  const int flat = blockIdx.y * 16 + blockIdx.x;
  const int bh = (flat & 7) * 4 + ((flat >> 3) & 3);
  const int qt = flat >> 5;

  const int tid  = threadIdx.x;
  const int lane = tid & 63, w = tid >> 6;
  const int quad = lane >> 4, l15 = lane & 15;
  const int sw0 = ((quad)     ^ (l15 & 7)) * 8;
  const int sw1 = ((quad + 4) ^ (l15 & 7)) * 8;

  const u16* qp = q  + (size_t)bh * 131072;
  const u16* kp = k  + (size_t)bh * 131072;
  const u16* vp = vt + (size_t)bh * 131072;

  bf16x8 qf[2][2];
#pragma unroll
  for (int qh = 0; qh < 2; qh++)
#pragma unroll
    for (int ks = 0; ks < 2; ks++)
      qf[qh][ks] = *(const bf16x8*)(qp + (size_t)(qt * 128 + w * 32 + qh * 16 + l15) * 64 + ks * 32 + quad * 8);

  f32x4 l_acc[2] = {};
  f32x4 o[2][4] = {};

  bf16x8 ones;
  {
    short one = (short)0x3F80;
    ones = (bf16x8){one, one, one, one, one, one, one, one};
  }

  u16* Pw = &P_lds[w * 16 * 136];

  stage_sw(kp, 64, K_lds[0], tid);

  for (int it = 0; it < 16; it++) {
    __syncthreads();   // drains prefetch (full prev compute was in flight)
    if (it < 15) stage_sw(kp + (size_t)(it + 1) * 8192, 64, K_lds[(it + 1) & 1], tid);
    const u16* Kb = K_lds[it & 1];
    const u16* vit = vp + it * 8192;

#pragma unroll
    for (int qh = 0; qh < 2; qh++) {
      // S phase: MFMA -> exp2 -> pack -> per-wave P (16 rows, reused per qh)
#pragma unroll
      for (int jt = 0; jt < 8; jt++) {
        bf16x8 kf0 = *(const bf16x8*)&Kb[(jt * 16 + l15) * 64 + sw0];
        bf16x8 kf1 = *(const bf16x8*)&Kb[(jt * 16 + l15) * 64 + sw1];
        f32x4 s = {0.f, 0.f, 0.f, 0.f};
        s = MFMA16(kf0, qf[qh][0], s);
        s = MFMA16(kf1, qf[qh][1], s);
        u32 pb[4];
#pragma unroll
        for (int r = 0; r < 4; r++) pb[r] = __float_as_uint(EXP2(s[r]));
        uint2 pk;
        pk.x = __builtin_amdgcn_perm(pb[1], pb[0], 0x07060302u);
        pk.y = __builtin_amdgcn_perm(pb[3], pb[2], 0x07060302u);
        *(uint2*)&Pw[l15 * 136 + jt * 16 + quad * 4] = pk;
      }

      // PV phase (vf double-buffered, same-wave LDS RAW handled by compiler)
      bf16x8 vf[2][4];
#pragma unroll
      for (int dt = 0; dt < 4; dt++)
        vf[0][dt] = *(const bf16x8*)(vit + (dt * 16 + l15) * 32 + quad * 8);
#pragma unroll
      for (int ks = 0; ks < 4; ks++) {
        if (ks < 3) {
#pragma unroll
          for (int dt = 0; dt < 4; dt++)
            vf[(ks + 1) & 1][dt] = *(const bf16x8*)(vit + (ks + 1) * 2048 + (dt * 16 + l15) * 32 + quad * 8);
        }
        bf16x8 pf = *(const bf16x8*)&Pw[l15 * 136 + ks * 32 + quad * 8];
        l_acc[qh] = MFMA16(pf, ones, l_acc[qh]);
#pragma unroll
        for (int dt = 0; dt < 4; dt++)
          o[qh][dt] = MFMA16(pf, vf[ks & 1][dt], o[qh][dt]);
      }
    }
  }

  // epilogue: normalize, transpose via per-wave LDS, write yhi/ylo planes
  const int b = bh >> 3, h = bh & 7;
  u32* Tw = (u32*)Pw;
#pragma unroll
  for (int qh = 0; qh < 2; qh++) {
#pragma unroll
    for (int r = 0; r < 4; r++) {
      float inv = 1.f / l_acc[qh][r];
#pragma unroll
      for (int dt = 0; dt < 4; dt++) {
        float val = o[qh][dt][r] * inv;
        u16 hi = f2bf(val);
        u16 lo = f2bf(val - bf2f(hi));
        Tw[(quad * 4 + r) * 68 + dt * 16 + l15] = (u32)hi | ((u32)lo << 16);
      }
    }
    int t = qt * 128 + w * 32 + qh * 16 + l15;
    size_t rowb = (size_t)(b * 2048 + t) * 512 + h * 64 + quad * 16;
    uint4 g0 = *(uint4*)&Tw[l15 * 68 + quad * 16 + 0];
    uint4 g1 = *(uint4*)&Tw[l15 * 68 + quad * 16 + 4];
    uint4 g2 = *(uint4*)&Tw[l15 * 68 + quad * 16 + 8];
    uint4 g3 = *(uint4*)&Tw[l15 * 68 + quad * 16 + 12];
    uint4 hi4, lo4;
    hi4.x = __builtin_amdgcn_perm(g0.y, g0.x, 0x05040100u);
    hi4.y = __builtin_amdgcn_perm(g0.w, g0.z, 0x05040100u);
    hi4.z = __builtin_amdgcn_perm(g1.y, g1.x, 0x05040100u);
    hi4.w = __builtin_amdgcn_perm(g1.w, g1.z, 0x05040100u);
    lo4.x = __builtin_amdgcn_perm(g0.y, g0.x, 0x07060302u);
    lo4.y = __builtin_amdgcn_perm(g0.w, g0.z, 0x07060302u);
    lo4.z = __builtin_amdgcn_perm(g1.y, g1.x, 0x07060302u);
    lo4.w = __builtin_amdgcn_perm(g1.w, g1.z, 0x07060302u);
    *(uint4*)&yb[rowb] = hi4;
    *(uint4*)&yb[(size_t)4 * 2048 * 512 + rowb] = lo4;
    hi4.x = __builtin_amdgcn_perm(g2.y, g2.x, 0x05040100u);
    hi4.y = __builtin_amdgcn_perm(g2.w, g2.z, 0x05040100u);
    hi4.z = __builtin_amdgcn_perm(g3.y, g3.x, 0x05040100u);
    hi4.w = __builtin_amdgcn_perm(g3.w, g3.z, 0x05040100u);
    lo4.x = __builtin_amdgcn_perm(g2.y, g2.x, 0x07060302u);
    lo4.y = __builtin_amdgcn_perm(g2.w, g2.z, 0x07060302u);
    lo4.z = __builtin_amdgcn_perm(g3.y, g3.x, 0x07060302u);
    lo4.w = __builtin_amdgcn_perm(g3.w, g3.z, 0x07060302u);
    *(uint4*)&yb[rowb + 8] = hi4;
    *(uint4*)&yb[(size_t)4 * 2048 * 512 + rowb + 8] = lo4;
  }
}

// ---------------- output projection (4-buffer hi/lo, XCD-banded) ---------
__global__ __launch_bounds__(256) void gemm_out(const u16* __restrict__ yhi,
                                                const u16* __restrict__ ylo,
                                                const u16* __restrict__ whi,
                                                const u16* __restrict__ wlo,
                                                const float* __restrict__ b_out,
                                                float* __restrict__ out) {
  __shared__ u16 Ah[64 * 72];
  __shared__ u16 Al[64 * 72];
  __shared__ u16 Bh[64 * 72];
  __shared__ u16 Bl[64 * 72];
  const int bid = blockIdx.x;
  const int xcd = bid & 7, rr = bid >> 3;
  const int m0 = (xcd * 16 + (rr & 15)) * 64;
  const int n0 = (rr >> 4) * 64;
  const int tid  = threadIdx.x;
  const int lane = tid & 63, w = tid >> 6;
  const int wm = w >> 1, wn = w & 1;
  const int quad = lane >> 4, l15 = lane & 15;

  f32x4 acc[2][2] = {};

  for (int k0 = 0; k0 < 512; k0 += 64) {
#pragma unroll
    for (int i = 0; i < 2; i++) {
      int vv = tid + i * 256;
      int row = vv >> 3;
      int cv  = (vv & 7) * 8;
      *(uint4*)&Ah[row * 72 + cv] = *(const uint4*)(yhi + (size_t)(m0 + row) * 512 + k0 + cv);
      *(uint4*)&Al[row * 72 + cv] = *(const uint4*)(ylo + (size_t)(m0 + row) * 512 + k0 + cv);
      *(uint4*)&Bh[row * 72 + cv] = *(const uint4*)(whi + (size_t)(n0 + row) * 512 + k0 + cv);
      *(uint4*)&Bl[row * 72 + cv] = *(const uint4*)(wlo + (size_t)(n0 + row) * 512 + k0 + cv);
    }
    __syncthreads();
#pragma unroll
    for (int ks = 0; ks < 2; ks++) {
      bf16x8 afh[2], afl[2], bfh[2], bfl[2];
#pragma unroll
      for (int ri = 0; ri < 2; ri++) {
        afh[ri] = *(const bf16x8*)&Ah[(wm * 32 + ri * 16 + l15) * 72 + ks * 32 + quad * 8];
        afl[ri] = *(const bf16x8*)&Al[(wm * 32 + ri * 16 + l15) * 72 + ks * 32 + quad * 8];
      }
#pragma unroll
      for (int ci = 0; ci < 2; ci++) {
        bfh[ci] = *(const bf16x8*)&Bh[(wn * 32 + ci * 16 + l15) * 72 + ks * 32 + quad * 8];
        bfl[ci] = *(const bf16x8*)&Bl[(wn * 32 + ci * 16 + l15) * 72 + ks * 32 + quad * 8];
      }
#pragma unroll
      for (int ri = 0; ri < 2; ri++)
#pragma unroll
        for (int ci = 0; ci < 2; ci++) {
          acc[ri][ci] = MFMA16(afh[ri], bfh[ci], acc[ri][ci]);
          acc[ri][ci] = MFMA16(afh[ri], bfl[ci], acc[ri][ci]);
          acc[ri][ci] = MFMA16(afl[ri], bfh[ci], acc[ri][ci]);
        }
    }
    __syncthreads();
  }

#pragma unroll
  for (int ri = 0; ri < 2; ri++) {
#pragma unroll
    for (int ci = 0; ci < 2; ci++) {
      int n = n0 + wn * 32 + ci * 16 + l15;
      float bias = b_out[n];
#pragma unroll
      for (int r = 0; r < 4; r++) {
        int m = m0 + wm * 32 + ri * 16 + quad * 4 + r;
        out[(size_t)m * 512 + n] = acc[ri][ci][r] + bias;
      }
    }
  }
}

// ---------------- launch ----------------
extern "C" void kernel_launch(void* const* d_in, const int* in_sizes, int n_in,
                              void* d_out, int out_size, void* d_ws, size_t ws_size,
                              hipStream_t stream) {
  const float* x      = (const float*)d_in[0];
  const float* W_attn = (const float*)d_in[1];
  const float* b_attn = (const float*)d_in[2];
  const float* W_out  = (const float*)d_in[3];
  const float* b_out  = (const float*)d_in[4];
  float* out = (float*)d_out;

  char* ws = (char*)d_ws;
  u16* xb   = (u16*)(ws + 0);                 //  8 MB  [8192][512]
  u16* wta  = (u16*)(ws + 8388608);           //  1.5MB [1536][512]
  u16* wtoh = (u16*)(ws + 9961472);           //  0.5MB [512][512]
  u16* wtol = (u16*)(ws + 10485760);          //  0.5MB
  u16* qb   = (u16*)(ws + 11010048);          //  8 MB  [bh][t][64] (pre-scaled)
  u16* kb   = (u16*)(ws + 19398656);          //  8 MB  [bh][t][64]
  u16* vtb  = (u16*)(ws + 27787264);          //  8 MB  V' frag-packed
  u16* yhi  = (u16*)(ws + 36175872);          //  8 MB  [B,T,C] (+8 MB lo plane)

  cast_x_kernel<<<4096, 256, 0, stream>>>(x, xb, 4 * 2048 * 512 / 4);
  trans_wa_kernel<<<dim3(24, 8), 256, 0, stream>>>(W_attn, wta);
  trans_wo_kernel<<<dim3(8, 8), 256, 0, stream>>>(W_out, wtoh, wtol);
  gemm_qkv<<<3072, 256, 0, stream>>>(xb, wta, b_attn, qb, kb, vtb);
  flash_attn<<<dim3(16, 32), 256, 0, stream>>>(qb, kb, vtb, yhi);
  gemm_out<<<1024, 256, 0, stream>>>(yhi, yhi + (size_t)4 * 2048 * 512, wtoh, wtol, b_out, out);
}